// Round 5
// baseline (922.186 us; speedup 1.0000x reference)
//
#include <hip/hip_runtime.h>
#include <hip/hip_bf16.h>

// JetGNN: 2-layer SAGEConv(mean) + ReLU + global_mean_pool + Linear(64->2)
// R1: hierarchical scan. R2: bucketed counting-sort CSR build.
// R3: dense weights-in-VGPR + sorted-batch pool run-flush (50MB->4MB atomics).
// R4: dense VGPR=72 showed compiler rematerialized weight loads in-loop ->
//     force float4 weight arrays, 8-node strips processed in PAIRS (2 indep
//     chains for MLP); agg neighbor loop unrolled x4 (4 gathers in flight).

#define WS_ALIGN 64
#define EPB 4096          // edges per block in bucket_scatter (256 thr x 16)
#define BSHIFT 10         // 1024 nodes per bucket
#define BNODES 1024

// ---------- pooling counts ----------

__global__ void cnt_kernel(const int* __restrict__ batch, int* __restrict__ cnt, int N) {
    int i = blockIdx.x * blockDim.x + threadIdx.x;
    if (i < N) atomicAdd(&cnt[batch[i]], 1);
}

// ---------- bucketed CSR construction ----------

__global__ __launch_bounds__(256) void bucket_hist_kernel(const int* __restrict__ dst,
                                                          int* __restrict__ bucketCount, int E) {
    __shared__ int hist[256];
    const int t = threadIdx.x;
    hist[t] = 0;
    __syncthreads();
    for (int e = blockIdx.x * blockDim.x + t; e < E; e += gridDim.x * blockDim.x)
        atomicAdd(&hist[dst[e] >> BSHIFT], 1);
    __syncthreads();
    if (hist[t] > 0) atomicAdd(&bucketCount[t], hist[t]);
}

__global__ __launch_bounds__(256) void bucket_scan_kernel(const int* __restrict__ bucketCount,
                                                          int* __restrict__ bucketBase,
                                                          int* __restrict__ bucketCursor,
                                                          int NB, int E) {
    __shared__ int s[256];
    const int t = threadIdx.x;
    int v = (t < NB) ? bucketCount[t] : 0;
    s[t] = v;
    __syncthreads();
    for (int off = 1; off < 256; off <<= 1) {
        int u = (t >= off) ? s[t - off] : 0;
        __syncthreads();
        s[t] += u;
        __syncthreads();
    }
    int excl = s[t] - v;
    if (t < NB) { bucketBase[t] = excl; bucketCursor[t] = excl; }
    if (t == 0) bucketBase[NB] = E;
}

__global__ __launch_bounds__(256) void bucket_scatter_kernel(const int* __restrict__ src,
                                                             const int* __restrict__ dst,
                                                             int* __restrict__ bucketCursor,
                                                             unsigned* __restrict__ bucketData,
                                                             int E, int NB) {
    __shared__ int hist[256];
    __shared__ int cur[256];
    const int t = threadIdx.x;
    hist[t] = 0;
    __syncthreads();
    const int eBase = blockIdx.x * EPB + t;
    int s[16], b[16], dl[16];
#pragma unroll
    for (int j = 0; j < 16; ++j) {
        int e = eBase + j * 256;
        if (e < E) {
            int d = dst[e];
            s[j]  = src[e];
            b[j]  = d >> BSHIFT;
            dl[j] = d & (BNODES - 1);
            atomicAdd(&hist[b[j]], 1);
        } else {
            b[j] = -1;
        }
    }
    __syncthreads();
    if (t < NB && hist[t] > 0) cur[t] = atomicAdd(&bucketCursor[t], hist[t]);
    __syncthreads();
#pragma unroll
    for (int j = 0; j < 16; ++j) {
        if (b[j] >= 0) {
            int pos = atomicAdd(&cur[b[j]], 1);
            bucketData[pos] = ((unsigned)s[j] << BSHIFT) | (unsigned)dl[j];
        }
    }
}

__global__ __launch_bounds__(256) void csr_build_kernel(const unsigned* __restrict__ bucketData,
                                                        const int* __restrict__ bucketBase,
                                                        int* __restrict__ offsets,
                                                        int* __restrict__ csr_src,
                                                        int N, int E, int NB) {
    __shared__ int cnt[BNODES];
    __shared__ int sscan[256];
    __shared__ int cur[BNODES];
    const int t   = threadIdx.x;
    const int bkt = blockIdx.x;
    const int beg = bucketBase[bkt];
    const int end = bucketBase[bkt + 1];
    for (int i = t; i < BNODES; i += 256) cnt[i] = 0;
    __syncthreads();
    for (int k = beg + t; k < end; k += 256)
        atomicAdd(&cnt[bucketData[k] & (BNODES - 1)], 1);
    __syncthreads();
    int local[4];
    int sum = 0;
#pragma unroll
    for (int j = 0; j < 4; ++j) { local[j] = sum; sum += cnt[t * 4 + j]; }
    sscan[t] = sum;
    __syncthreads();
    for (int off = 1; off < 256; off <<= 1) {
        int v = (t >= off) ? sscan[t - off] : 0;
        __syncthreads();
        sscan[t] += v;
        __syncthreads();
    }
    int base = (t > 0) ? sscan[t - 1] : 0;
#pragma unroll
    for (int j = 0; j < 4; ++j) cur[t * 4 + j] = base + local[j];
    __syncthreads();
    for (int i = t; i < BNODES; i += 256) {
        int node = (bkt << BSHIFT) + i;
        if (node <= N) offsets[node] = beg + cur[i];
    }
    if (bkt == NB - 1 && t == 0 && (NB << BSHIFT) == N) offsets[N] = E;
    __syncthreads();
    for (int k = beg + t; k < end; k += 256) {
        unsigned v = bucketData[k];
        int d   = (int)(v & (BNODES - 1));
        int pos = beg + atomicAdd(&cur[d], 1);
        csr_src[pos] = (int)(v >> BSHIFT);
    }
}

// ---------- mean aggregation (node-parallel, D/4 threads per node) ----------
// R4: neighbor loop unrolled x4 -> 4 independent gathers in flight.

template <int D>
__global__ void agg_kernel(const float* __restrict__ feat,
                           const int* __restrict__ csr_src,
                           const int* __restrict__ offsets,
                           float* __restrict__ agg, int N) {
    constexpr int TPN = D / 4;
    int tid  = blockIdx.x * blockDim.x + threadIdx.x;
    int node = tid / TPN;
    int part = tid % TPN;
    if (node >= N) return;
    const int beg = offsets[node];
    const int end = offsets[node + 1];
    float4 acc = make_float4(0.f, 0.f, 0.f, 0.f);
    int k = beg;
    for (; k + 4 <= end; k += 4) {
        const int s0 = csr_src[k + 0];
        const int s1 = csr_src[k + 1];
        const int s2 = csr_src[k + 2];
        const int s3 = csr_src[k + 3];
        const float4 v0 = *reinterpret_cast<const float4*>(feat + (size_t)s0 * D + part * 4);
        const float4 v1 = *reinterpret_cast<const float4*>(feat + (size_t)s1 * D + part * 4);
        const float4 v2 = *reinterpret_cast<const float4*>(feat + (size_t)s2 * D + part * 4);
        const float4 v3 = *reinterpret_cast<const float4*>(feat + (size_t)s3 * D + part * 4);
        acc.x += (v0.x + v1.x) + (v2.x + v3.x);
        acc.y += (v0.y + v1.y) + (v2.y + v3.y);
        acc.z += (v0.z + v1.z) + (v2.z + v3.z);
        acc.w += (v0.w + v1.w) + (v2.w + v3.w);
    }
    for (; k < end; ++k) {
        const int s = csr_src[k];
        const float4 v = *reinterpret_cast<const float4*>(feat + (size_t)s * D + part * 4);
        acc.x += v.x; acc.y += v.y; acc.z += v.z; acc.w += v.w;
    }
    const float inv = 1.0f / fmaxf((float)(end - beg), 1.0f);
    acc.x *= inv; acc.y *= inv; acc.z *= inv; acc.w *= inv;
    *reinterpret_cast<float4*>(agg + (size_t)node * D + part * 4) = acc;
}

// ---------- dense: lane = output channel, wave = 8-node strip in pairs ----------

template <int DIN, bool POOL>
__launch_bounds__(256)
__global__ void dense_kernel(const float* __restrict__ agg,
                             const float* __restrict__ xin,
                             const float* __restrict__ Wl,
                             const float* __restrict__ Wr,
                             const float* __restrict__ bias,
                             float* __restrict__ hout,
                             const int* __restrict__ batch,
                             float* __restrict__ pool_sum,
                             int N) {
    constexpr int NC4 = DIN / 4;
    const int lane = threadIdx.x & 63;
    const int wave = threadIdx.x >> 6;
    float4 wl[NC4], wr[NC4];
#pragma unroll
    for (int c4 = 0; c4 < NC4; ++c4) {
        wl[c4] = *reinterpret_cast<const float4*>(Wl + (size_t)lane * DIN + c4 * 4);
        wr[c4] = *reinterpret_cast<const float4*>(Wr + (size_t)lane * DIN + c4 * 4);
    }
    const float b = bias[lane];
    const int nodeBeg = (blockIdx.x * 4 + wave) * 8;
    float accg = 0.0f;
    int gcur = -1;
#pragma unroll
    for (int i = 0; i < 8; i += 2) {
        const int n0 = nodeBeg + i;
        const int n1 = n0 + 1;
        if (n0 >= N) break;                              // wave-uniform
        const bool has1 = (n1 < N);
        const int n1c = has1 ? n1 : n0;
        const float* a0 = agg + (size_t)n0 * DIN;
        const float* x0 = xin + (size_t)n0 * DIN;
        const float* a1 = agg + (size_t)n1c * DIN;
        const float* x1 = xin + (size_t)n1c * DIN;
        float acc0 = b, acc1 = b;
#pragma unroll
        for (int c4 = 0; c4 < NC4; ++c4) {
            const float4 av0 = *reinterpret_cast<const float4*>(a0 + c4 * 4);
            const float4 xv0 = *reinterpret_cast<const float4*>(x0 + c4 * 4);
            const float4 av1 = *reinterpret_cast<const float4*>(a1 + c4 * 4);
            const float4 xv1 = *reinterpret_cast<const float4*>(x1 + c4 * 4);
            acc0 = fmaf(av0.x, wl[c4].x, acc0);
            acc1 = fmaf(av1.x, wl[c4].x, acc1);
            acc0 = fmaf(av0.y, wl[c4].y, acc0);
            acc1 = fmaf(av1.y, wl[c4].y, acc1);
            acc0 = fmaf(av0.z, wl[c4].z, acc0);
            acc1 = fmaf(av1.z, wl[c4].z, acc1);
            acc0 = fmaf(av0.w, wl[c4].w, acc0);
            acc1 = fmaf(av1.w, wl[c4].w, acc1);
            acc0 = fmaf(xv0.x, wr[c4].x, acc0);
            acc1 = fmaf(xv1.x, wr[c4].x, acc1);
            acc0 = fmaf(xv0.y, wr[c4].y, acc0);
            acc1 = fmaf(xv1.y, wr[c4].y, acc1);
            acc0 = fmaf(xv0.z, wr[c4].z, acc0);
            acc1 = fmaf(xv1.z, wr[c4].z, acc1);
            acc0 = fmaf(xv0.w, wr[c4].w, acc0);
            acc1 = fmaf(xv1.w, wr[c4].w, acc1);
        }
        acc0 = fmaxf(acc0, 0.0f);
        acc1 = fmaxf(acc1, 0.0f);
        if (POOL) {
            const int g0 = batch[n0];                    // wave-uniform, sorted
            if (g0 != gcur) {
                if (gcur >= 0) atomicAdd(&pool_sum[(size_t)gcur * 64 + lane], accg);
                gcur = g0; accg = 0.0f;
            }
            accg += acc0;
            if (has1) {
                const int g1 = batch[n1];
                if (g1 != gcur) {
                    atomicAdd(&pool_sum[(size_t)gcur * 64 + lane], accg);
                    gcur = g1; accg = 0.0f;
                }
                accg += acc1;
            }
        } else {
            hout[(size_t)n0 * 64 + lane] = acc0;
            if (has1) hout[(size_t)n1 * 64 + lane] = acc1;
        }
    }
    if (POOL && gcur >= 0) atomicAdd(&pool_sum[(size_t)gcur * 64 + lane], accg);
}

// ---------- head ----------

__global__ void final_kernel(const float* __restrict__ pool_sum,
                             const int* __restrict__ cnt,
                             const float* __restrict__ W_lin,
                             const float* __restrict__ b_lin,
                             float* __restrict__ out, int G) {
    int t = blockIdx.x * blockDim.x + threadIdx.x;
    if (t >= G * 2) return;
    int g = t >> 1, o = t & 1;
    float inv = 1.0f / fmaxf((float)cnt[g], 1.0f);
    float acc = b_lin[o];
#pragma unroll
    for (int c = 0; c < 64; ++c)
        acc = fmaf(pool_sum[(size_t)g * 64 + c] * inv, W_lin[o * 64 + c], acc);
    out[t] = acc;
}

extern "C" void kernel_launch(void* const* d_in, const int* in_sizes, int n_in,
                              void* d_out, int out_size, void* d_ws, size_t ws_size,
                              hipStream_t stream) {
    const float* x     = (const float*)d_in[0];
    const int*   ei    = (const int*)d_in[1];
    const int*   batch = (const int*)d_in[2];
    const float* W1_l  = (const float*)d_in[3];
    const float* b1    = (const float*)d_in[4];
    const float* W1_r  = (const float*)d_in[5];
    const float* W2_l  = (const float*)d_in[6];
    const float* b2    = (const float*)d_in[7];
    const float* W2_r  = (const float*)d_in[8];
    const float* W_lin = (const float*)d_in[9];
    const float* b_lin = (const float*)d_in[10];

    const int N = in_sizes[0] / 32;
    const int E = in_sizes[1] / 2;
    const int G = out_size / 2;
    const int* src = ei;
    const int* dst = ei + E;
    const int NB = (N + BNODES - 1) >> BSHIFT;   // 196 for N=200000

    char* p = (char*)d_ws;
    auto carve = [&](size_t bytes) -> void* {
        void* r = (void*)p;
        p += (bytes + (WS_ALIGN - 1)) / WS_ALIGN * WS_ALIGN;
        return r;
    };
    int*      bucketCount  = (int*)carve(256 * 4);
    int*      bucketBase   = (int*)carve(257 * 4);
    int*      bucketCursor = (int*)carve(256 * 4);
    unsigned* bucketData   = (unsigned*)carve((size_t)E * 4);
    int*      offsets      = (int*)carve((size_t)(N + 1) * 4);
    int*      csr_src      = (int*)carve((size_t)E * 4);
    float*    agg          = (float*)carve((size_t)N * 64 * 4);
    float*    h1           = (float*)carve((size_t)N * 64 * 4);
    float*    pool         = (float*)carve((size_t)G * 64 * 4);
    int*      cnt          = (int*)carve((size_t)G * 4);
    float*    out          = (float*)d_out;

    hipMemsetAsync(bucketCount, 0, 256 * 4, stream);
    hipMemsetAsync(pool, 0, (size_t)G * 64 * 4, stream);
    hipMemsetAsync(cnt, 0, (size_t)G * 4, stream);

    const int TB = 256;
    cnt_kernel<<<(N + TB - 1) / TB, TB, 0, stream>>>(batch, cnt, N);
    bucket_hist_kernel<<<1024, TB, 0, stream>>>(dst, bucketCount, E);
    bucket_scan_kernel<<<1, TB, 0, stream>>>(bucketCount, bucketBase, bucketCursor, NB, E);
    bucket_scatter_kernel<<<(E + EPB - 1) / EPB, TB, 0, stream>>>(src, dst, bucketCursor,
                                                                  bucketData, E, NB);
    csr_build_kernel<<<NB, TB, 0, stream>>>(bucketData, bucketBase, offsets, csr_src, N, E, NB);

    // layer 1: aggregate x (D=32), dense 32->64 + relu -> h1
    agg_kernel<32><<<((size_t)N * 8 + TB - 1) / TB, TB, 0, stream>>>(x, csr_src, offsets, agg, N);
    dense_kernel<32, false><<<(N + 31) / 32, TB, 0, stream>>>(agg, x, W1_l, W1_r, b1, h1,
                                                              nullptr, nullptr, N);

    // layer 2: aggregate h1 (D=64), dense 64->64 + relu fused with pooling
    agg_kernel<64><<<((size_t)N * 16 + TB - 1) / TB, TB, 0, stream>>>(h1, csr_src, offsets, agg, N);
    dense_kernel<64, true><<<(N + 31) / 32, TB, 0, stream>>>(agg, h1, W2_l, W2_r, b2, nullptr,
                                                             batch, pool, N);

    final_kernel<<<(G * 2 + TB - 1) / TB, TB, 0, stream>>>(pool, cnt, W_lin, b_lin, out, G);
}

// Round 6
// 769.175 us; speedup vs baseline: 1.1989x; 1.1989x over previous
//
#include <hip/hip_runtime.h>
#include <hip/hip_bf16.h>

// JetGNN: 2-layer SAGEConv(mean) + ReLU + global_mean_pool + Linear(64->2)
// R1: hierarchical scan. R2: bucketed counting-sort CSR build.
// R3: dense weights "in VGPR" (compiler rematerialized, 172us) + run-flush pool.
// R4: forcing weight arrays -> VGPR 204, occupancy 11.5%, dense64 382us. BAD.
//     agg x4 unroll was a ~95us WIN - kept.
// R5: dense weights in LDS, row stride DIN+4 (16B-aligned, odd float4 stride
//     -> conflict-free-equivalent b128 reads), node pairs for 2 indep FMA
//     chains. VGPR back down, VALU-bound inner loop.

#define WS_ALIGN 64
#define EPB 4096          // edges per block in bucket_scatter (256 thr x 16)
#define BSHIFT 10         // 1024 nodes per bucket
#define BNODES 1024

// ---------- pooling counts ----------

__global__ void cnt_kernel(const int* __restrict__ batch, int* __restrict__ cnt, int N) {
    int i = blockIdx.x * blockDim.x + threadIdx.x;
    if (i < N) atomicAdd(&cnt[batch[i]], 1);
}

// ---------- bucketed CSR construction ----------

__global__ __launch_bounds__(256) void bucket_hist_kernel(const int* __restrict__ dst,
                                                          int* __restrict__ bucketCount, int E) {
    __shared__ int hist[256];
    const int t = threadIdx.x;
    hist[t] = 0;
    __syncthreads();
    for (int e = blockIdx.x * blockDim.x + t; e < E; e += gridDim.x * blockDim.x)
        atomicAdd(&hist[dst[e] >> BSHIFT], 1);
    __syncthreads();
    if (hist[t] > 0) atomicAdd(&bucketCount[t], hist[t]);
}

__global__ __launch_bounds__(256) void bucket_scan_kernel(const int* __restrict__ bucketCount,
                                                          int* __restrict__ bucketBase,
                                                          int* __restrict__ bucketCursor,
                                                          int NB, int E) {
    __shared__ int s[256];
    const int t = threadIdx.x;
    int v = (t < NB) ? bucketCount[t] : 0;
    s[t] = v;
    __syncthreads();
    for (int off = 1; off < 256; off <<= 1) {
        int u = (t >= off) ? s[t - off] : 0;
        __syncthreads();
        s[t] += u;
        __syncthreads();
    }
    int excl = s[t] - v;
    if (t < NB) { bucketBase[t] = excl; bucketCursor[t] = excl; }
    if (t == 0) bucketBase[NB] = E;
}

__global__ __launch_bounds__(256) void bucket_scatter_kernel(const int* __restrict__ src,
                                                             const int* __restrict__ dst,
                                                             int* __restrict__ bucketCursor,
                                                             unsigned* __restrict__ bucketData,
                                                             int E, int NB) {
    __shared__ int hist[256];
    __shared__ int cur[256];
    const int t = threadIdx.x;
    hist[t] = 0;
    __syncthreads();
    const int eBase = blockIdx.x * EPB + t;
    int s[16], b[16], dl[16];
#pragma unroll
    for (int j = 0; j < 16; ++j) {
        int e = eBase + j * 256;
        if (e < E) {
            int d = dst[e];
            s[j]  = src[e];
            b[j]  = d >> BSHIFT;
            dl[j] = d & (BNODES - 1);
            atomicAdd(&hist[b[j]], 1);
        } else {
            b[j] = -1;
        }
    }
    __syncthreads();
    if (t < NB && hist[t] > 0) cur[t] = atomicAdd(&bucketCursor[t], hist[t]);
    __syncthreads();
#pragma unroll
    for (int j = 0; j < 16; ++j) {
        if (b[j] >= 0) {
            int pos = atomicAdd(&cur[b[j]], 1);
            bucketData[pos] = ((unsigned)s[j] << BSHIFT) | (unsigned)dl[j];
        }
    }
}

__global__ __launch_bounds__(256) void csr_build_kernel(const unsigned* __restrict__ bucketData,
                                                        const int* __restrict__ bucketBase,
                                                        int* __restrict__ offsets,
                                                        int* __restrict__ csr_src,
                                                        int N, int E, int NB) {
    __shared__ int cnt[BNODES];
    __shared__ int sscan[256];
    __shared__ int cur[BNODES];
    const int t   = threadIdx.x;
    const int bkt = blockIdx.x;
    const int beg = bucketBase[bkt];
    const int end = bucketBase[bkt + 1];
    for (int i = t; i < BNODES; i += 256) cnt[i] = 0;
    __syncthreads();
    for (int k = beg + t; k < end; k += 256)
        atomicAdd(&cnt[bucketData[k] & (BNODES - 1)], 1);
    __syncthreads();
    int local[4];
    int sum = 0;
#pragma unroll
    for (int j = 0; j < 4; ++j) { local[j] = sum; sum += cnt[t * 4 + j]; }
    sscan[t] = sum;
    __syncthreads();
    for (int off = 1; off < 256; off <<= 1) {
        int v = (t >= off) ? sscan[t - off] : 0;
        __syncthreads();
        sscan[t] += v;
        __syncthreads();
    }
    int base = (t > 0) ? sscan[t - 1] : 0;
#pragma unroll
    for (int j = 0; j < 4; ++j) cur[t * 4 + j] = base + local[j];
    __syncthreads();
    for (int i = t; i < BNODES; i += 256) {
        int node = (bkt << BSHIFT) + i;
        if (node <= N) offsets[node] = beg + cur[i];
    }
    if (bkt == NB - 1 && t == 0 && (NB << BSHIFT) == N) offsets[N] = E;
    __syncthreads();
    for (int k = beg + t; k < end; k += 256) {
        unsigned v = bucketData[k];
        int d   = (int)(v & (BNODES - 1));
        int pos = beg + atomicAdd(&cur[d], 1);
        csr_src[pos] = (int)(v >> BSHIFT);
    }
}

// ---------- mean aggregation (node-parallel, D/4 threads per node) ----------
// R4: neighbor loop unrolled x4 -> 4 independent gathers in flight (WIN ~95us).

template <int D>
__global__ void agg_kernel(const float* __restrict__ feat,
                           const int* __restrict__ csr_src,
                           const int* __restrict__ offsets,
                           float* __restrict__ agg, int N) {
    constexpr int TPN = D / 4;
    int tid  = blockIdx.x * blockDim.x + threadIdx.x;
    int node = tid / TPN;
    int part = tid % TPN;
    if (node >= N) return;
    const int beg = offsets[node];
    const int end = offsets[node + 1];
    float4 acc = make_float4(0.f, 0.f, 0.f, 0.f);
    int k = beg;
    for (; k + 4 <= end; k += 4) {
        const int s0 = csr_src[k + 0];
        const int s1 = csr_src[k + 1];
        const int s2 = csr_src[k + 2];
        const int s3 = csr_src[k + 3];
        const float4 v0 = *reinterpret_cast<const float4*>(feat + (size_t)s0 * D + part * 4);
        const float4 v1 = *reinterpret_cast<const float4*>(feat + (size_t)s1 * D + part * 4);
        const float4 v2 = *reinterpret_cast<const float4*>(feat + (size_t)s2 * D + part * 4);
        const float4 v3 = *reinterpret_cast<const float4*>(feat + (size_t)s3 * D + part * 4);
        acc.x += (v0.x + v1.x) + (v2.x + v3.x);
        acc.y += (v0.y + v1.y) + (v2.y + v3.y);
        acc.z += (v0.z + v1.z) + (v2.z + v3.z);
        acc.w += (v0.w + v1.w) + (v2.w + v3.w);
    }
    for (; k < end; ++k) {
        const int s = csr_src[k];
        const float4 v = *reinterpret_cast<const float4*>(feat + (size_t)s * D + part * 4);
        acc.x += v.x; acc.y += v.y; acc.z += v.z; acc.w += v.w;
    }
    const float inv = 1.0f / fmaxf((float)(end - beg), 1.0f);
    acc.x *= inv; acc.y *= inv; acc.z *= inv; acc.w *= inv;
    *reinterpret_cast<float4*>(agg + (size_t)node * D + part * 4) = acc;
}

// ---------- dense: lane=out channel; weights in LDS (stride DIN+4);
//            node pairs -> 2 independent FMA chains ----------

template <int DIN, bool POOL, int STRIP>
__launch_bounds__(256)
__global__ void dense_kernel(const float* __restrict__ agg,
                             const float* __restrict__ xin,
                             const float* __restrict__ Wl,
                             const float* __restrict__ Wr,
                             const float* __restrict__ bias,
                             float* __restrict__ hout,
                             const int* __restrict__ batch,
                             float* __restrict__ pool_sum,
                             int N) {
    constexpr int PAD = DIN + 4;          // 16B-aligned rows; PAD/4 odd -> no bank clustering
    constexpr int NC4 = DIN / 4;
    __shared__ float wls[64 * PAD];
    __shared__ float wrs[64 * PAD];
    const int tid = threadIdx.x;
    for (int i = tid; i < 64 * DIN; i += 256) {
        const int o = i / DIN, c = i % DIN;
        wls[o * PAD + c] = Wl[i];
        wrs[o * PAD + c] = Wr[i];
    }
    __syncthreads();
    const int lane = tid & 63;
    const int wave = tid >> 6;
    const float* wlp = wls + lane * PAD;
    const float* wrp = wrs + lane * PAD;
    const float b = bias[lane];
    const int nodeBeg = (blockIdx.x * 4 + wave) * STRIP;
    float accg = 0.0f;
    int gcur = -1;
    for (int i = 0; i < STRIP; i += 2) {
        const int n0 = nodeBeg + i;
        const int n1 = n0 + 1;
        if (n0 >= N) break;                              // wave-uniform
        const bool has1 = (n1 < N);
        const int n1c = has1 ? n1 : n0;
        const float* a0 = agg + (size_t)n0 * DIN;
        const float* x0 = xin + (size_t)n0 * DIN;
        const float* a1 = agg + (size_t)n1c * DIN;
        const float* x1 = xin + (size_t)n1c * DIN;
        float acc0 = b, acc1 = b;
#pragma unroll
        for (int c4 = 0; c4 < NC4; ++c4) {
            const float4 wlv = *reinterpret_cast<const float4*>(wlp + c4 * 4);
            const float4 wrv = *reinterpret_cast<const float4*>(wrp + c4 * 4);
            const float4 av0 = *reinterpret_cast<const float4*>(a0 + c4 * 4);
            const float4 xv0 = *reinterpret_cast<const float4*>(x0 + c4 * 4);
            const float4 av1 = *reinterpret_cast<const float4*>(a1 + c4 * 4);
            const float4 xv1 = *reinterpret_cast<const float4*>(x1 + c4 * 4);
            acc0 = fmaf(av0.x, wlv.x, acc0);
            acc1 = fmaf(av1.x, wlv.x, acc1);
            acc0 = fmaf(av0.y, wlv.y, acc0);
            acc1 = fmaf(av1.y, wlv.y, acc1);
            acc0 = fmaf(av0.z, wlv.z, acc0);
            acc1 = fmaf(av1.z, wlv.z, acc1);
            acc0 = fmaf(av0.w, wlv.w, acc0);
            acc1 = fmaf(av1.w, wlv.w, acc1);
            acc0 = fmaf(xv0.x, wrv.x, acc0);
            acc1 = fmaf(xv1.x, wrv.x, acc1);
            acc0 = fmaf(xv0.y, wrv.y, acc0);
            acc1 = fmaf(xv1.y, wrv.y, acc1);
            acc0 = fmaf(xv0.z, wrv.z, acc0);
            acc1 = fmaf(xv1.z, wrv.z, acc1);
            acc0 = fmaf(xv0.w, wrv.w, acc0);
            acc1 = fmaf(xv1.w, wrv.w, acc1);
        }
        acc0 = fmaxf(acc0, 0.0f);
        acc1 = fmaxf(acc1, 0.0f);
        if (POOL) {
            const int g0 = batch[n0];                    // wave-uniform, sorted
            if (g0 != gcur) {
                if (gcur >= 0) atomicAdd(&pool_sum[(size_t)gcur * 64 + lane], accg);
                gcur = g0; accg = 0.0f;
            }
            accg += acc0;
            if (has1) {
                const int g1 = batch[n1];
                if (g1 != gcur) {
                    atomicAdd(&pool_sum[(size_t)gcur * 64 + lane], accg);
                    gcur = g1; accg = 0.0f;
                }
                accg += acc1;
            }
        } else {
            hout[(size_t)n0 * 64 + lane] = acc0;
            if (has1) hout[(size_t)n1 * 64 + lane] = acc1;
        }
    }
    if (POOL && gcur >= 0) atomicAdd(&pool_sum[(size_t)gcur * 64 + lane], accg);
}

// ---------- head ----------

__global__ void final_kernel(const float* __restrict__ pool_sum,
                             const int* __restrict__ cnt,
                             const float* __restrict__ W_lin,
                             const float* __restrict__ b_lin,
                             float* __restrict__ out, int G) {
    int t = blockIdx.x * blockDim.x + threadIdx.x;
    if (t >= G * 2) return;
    int g = t >> 1, o = t & 1;
    float inv = 1.0f / fmaxf((float)cnt[g], 1.0f);
    float acc = b_lin[o];
#pragma unroll
    for (int c = 0; c < 64; ++c)
        acc = fmaf(pool_sum[(size_t)g * 64 + c] * inv, W_lin[o * 64 + c], acc);
    out[t] = acc;
}

extern "C" void kernel_launch(void* const* d_in, const int* in_sizes, int n_in,
                              void* d_out, int out_size, void* d_ws, size_t ws_size,
                              hipStream_t stream) {
    const float* x     = (const float*)d_in[0];
    const int*   ei    = (const int*)d_in[1];
    const int*   batch = (const int*)d_in[2];
    const float* W1_l  = (const float*)d_in[3];
    const float* b1    = (const float*)d_in[4];
    const float* W1_r  = (const float*)d_in[5];
    const float* W2_l  = (const float*)d_in[6];
    const float* b2    = (const float*)d_in[7];
    const float* W2_r  = (const float*)d_in[8];
    const float* W_lin = (const float*)d_in[9];
    const float* b_lin = (const float*)d_in[10];

    const int N = in_sizes[0] / 32;
    const int E = in_sizes[1] / 2;
    const int G = out_size / 2;
    const int* src = ei;
    const int* dst = ei + E;
    const int NB = (N + BNODES - 1) >> BSHIFT;   // 196 for N=200000

    char* p = (char*)d_ws;
    auto carve = [&](size_t bytes) -> void* {
        void* r = (void*)p;
        p += (bytes + (WS_ALIGN - 1)) / WS_ALIGN * WS_ALIGN;
        return r;
    };
    int*      bucketCount  = (int*)carve(256 * 4);
    int*      bucketBase   = (int*)carve(257 * 4);
    int*      bucketCursor = (int*)carve(256 * 4);
    unsigned* bucketData   = (unsigned*)carve((size_t)E * 4);
    int*      offsets      = (int*)carve((size_t)(N + 1) * 4);
    int*      csr_src      = (int*)carve((size_t)E * 4);
    float*    agg          = (float*)carve((size_t)N * 64 * 4);
    float*    h1           = (float*)carve((size_t)N * 64 * 4);
    float*    pool         = (float*)carve((size_t)G * 64 * 4);
    int*      cnt          = (int*)carve((size_t)G * 4);
    float*    out          = (float*)d_out;

    hipMemsetAsync(bucketCount, 0, 256 * 4, stream);
    hipMemsetAsync(pool, 0, (size_t)G * 64 * 4, stream);
    hipMemsetAsync(cnt, 0, (size_t)G * 4, stream);

    const int TB = 256;
    cnt_kernel<<<(N + TB - 1) / TB, TB, 0, stream>>>(batch, cnt, N);
    bucket_hist_kernel<<<1024, TB, 0, stream>>>(dst, bucketCount, E);
    bucket_scan_kernel<<<1, TB, 0, stream>>>(bucketCount, bucketBase, bucketCursor, NB, E);
    bucket_scatter_kernel<<<(E + EPB - 1) / EPB, TB, 0, stream>>>(src, dst, bucketCursor,
                                                                  bucketData, E, NB);
    csr_build_kernel<<<NB, TB, 0, stream>>>(bucketData, bucketBase, offsets, csr_src, N, E, NB);

    // layer 1: aggregate x (D=32), dense 32->64 + relu -> h1
    agg_kernel<32><<<((size_t)N * 8 + TB - 1) / TB, TB, 0, stream>>>(x, csr_src, offsets, agg, N);
    dense_kernel<32, false, 16><<<(N + 63) / 64, TB, 0, stream>>>(agg, x, W1_l, W1_r, b1, h1,
                                                                  nullptr, nullptr, N);

    // layer 2: aggregate h1 (D=64), dense 64->64 + relu fused with pooling
    agg_kernel<64><<<((size_t)N * 16 + TB - 1) / TB, TB, 0, stream>>>(h1, csr_src, offsets, agg, N);
    dense_kernel<64, true, 16><<<(N + 63) / 64, TB, 0, stream>>>(agg, h1, W2_l, W2_r, b2, nullptr,
                                                                 batch, pool, N);

    final_kernel<<<(G * 2 + TB - 1) / TB, TB, 0, stream>>>(pool, cnt, W_lin, b_lin, out, G);
}